// Round 6
// baseline (462.203 us; speedup 1.0000x reference)
//
#include <hip/hip_runtime.h>
#include <math.h>

#define NV 6890
#define NF 13776
#define NVPAD 6912            // 27 * 256
#define NFPAD 13824           // 64 * 216 (zero-padded triangles)
#define QTR 1728              // NVPAD/4: thread handles pt, +QTR, +2QTR, +3QTR
#define PBLK 7                // point blocks: 7*256 = 1792 >= QTR
#define TCH 64                // triangle chunks
#define TPC 216               // NFPAD / TCH, compile-time uniform trip count
#define WN_BLOCKS (PBLK*TCH)  // 448
#define V2V_BLOCKS 1723       // ceil(NV / 4 rows per block)
#define RED_BLOCKS 27         // 27*256 covers NV
#define WN_THRES 0.99
#define EUCL_THRES 0.02f

// ws layout (bytes) — same 2.54MB proven footprint:
//  [0,4)                       : gm format flag: 0=u8, 1=i32, 2=f32
//  [64, 64+NFPAD*48)           : tris12 (zero-padded past NF)
//  [+0, +NVPAD*16)             : x4: (x,y,z,|x|^2), zero-padded past NV
//  [+0, +TCH*NVPAD*4)          : partial omega sums (f32 chunk sums)
#define WS_TRIS_OFF   64
#define WS_X4_OFF     (64 + NFPAD*48)            // 663616
#define WS_PART_OFF   (WS_X4_OFF + NVPAD*16)     // 774208
// end: 774208 + 64*6912*4 = 2,543,680 bytes

__global__ __launch_bounds__(256) void prep_kernel(
    const float* __restrict__ verts, const int* __restrict__ faces,
    const unsigned char* __restrict__ gm_bytes,
    float* __restrict__ tris12, float* __restrict__ x4, int* __restrict__ flag)
{
    int t = blockIdx.x * 256 + threadIdx.x;

    if (t < NFPAD) {
        float* o = tris12 + (size_t)t * 12;
        if (t < NF) {
            int ia = faces[t*3+0], ib = faces[t*3+1], ic = faces[t*3+2];
            o[0]  = verts[ia*3+0]; o[1]  = verts[ia*3+1]; o[2]  = verts[ia*3+2]; o[3]  = 0.f;
            o[4]  = verts[ib*3+0]; o[5]  = verts[ib*3+1]; o[6]  = verts[ib*3+2]; o[7]  = 0.f;
            o[8]  = verts[ic*3+0]; o[9]  = verts[ic*3+1]; o[10] = verts[ic*3+2]; o[11] = 0.f;
        } else {
            #pragma unroll
            for (int q = 0; q < 12; ++q) o[q] = 0.f;   // degenerate tri -> omega 0
        }
    }
    if (t < NVPAD) {
        if (t < NV) {
            float x = verts[t*3+0], y = verts[t*3+1], z = verts[t*3+2];
            x4[t*4+0] = x; x4[t*4+1] = y; x4[t*4+2] = z;
            x4[t*4+3] = (x*x + y*y) + z*z;   // match jnp sum order
        } else {
            x4[t*4+0] = 0.f; x4[t*4+1] = 0.f; x4[t*4+2] = 0.f; x4[t*4+3] = 0.f;
        }
    }
    // geomask dtype detection: first wave of block 0 scans 4096 bytes
    if (blockIdx.x == 0 && threadIdx.x < 64) {
        int lane = threadIdx.x;
        bool any3F = false, anyNZmod = false;
        for (int k = 0; k < 64; ++k) {
            int off = lane * 64 + k;
            unsigned char b = gm_bytes[off];
            if ((off & 3) == 3 && (b == 0x3F || b == 0xBF)) any3F = true;
            if ((off & 3) != 0 && b != 0) anyNZmod = true;
        }
        unsigned long long m3F = __ballot(any3F);
        unsigned long long mNZ = __ballot(anyNZmod);
        if (lane == 0) {
            *flag = m3F ? 2 : (mNZ ? 0 : 1);
        }
    }
}

// SLEEF-style atan2: v_rcp instead of IEEE divide, no inf/nan ladder.
// The fmaxf(mx,1e-37f) guard is LOAD-BEARING: degenerate pairs (point ==
// triangle vertex) give det=denom=0 and must produce 0, not NaN.
__device__ __forceinline__ float fast_atan2f(float y, float x)
{
    float ay = __builtin_fabsf(y), ax = __builtin_fabsf(x);
    float mx = fmaxf(ax, ay);
    float mn = fminf(ax, ay);
    float r  = __builtin_amdgcn_rcpf(fmaxf(mx, 1e-37f));
    float t  = mn * r;
    float s  = t * t;
    float u  =              0.00282363896258175373077393f;
    u = fmaf(u, s, -0.0159569028764963150024414f);
    u = fmaf(u, s,  0.0425049886107444763183594f);
    u = fmaf(u, s, -0.0748900920152664184570312f);
    u = fmaf(u, s,  0.106347933411598205566406f);
    u = fmaf(u, s, -0.142027363181114196777344f);
    u = fmaf(u, s,  0.199926957488059997558594f);
    u = fmaf(u, s, -0.333331018686294555664062f);
    float p = fmaf(s * u, t, t);                       // atan(t), t in [0,1]
    p = (ay > ax)  ? (1.5707963267948966f - p) : p;
    p = (x < 0.0f) ? (3.14159265358979323846f - p) : p;
    return copysignf(p, y);
}

// omega/2 for one (point, triangle); bit-identical math to the passing version
#define TRI_OMEGA(A, B, C, PX, PY, PZ, S)                                 \
    {                                                                     \
        float ax = A.x - PX, ay = A.y - PY, az = A.z - PZ;                \
        float bx = B.x - PX, by = B.y - PY, bz = B.z - PZ;                \
        float cx = C.x - PX, cy = C.y - PY, cz = C.z - PZ;                \
        float la = __builtin_amdgcn_sqrtf((ax*ax + ay*ay) + az*az);       \
        float lb = __builtin_amdgcn_sqrtf((bx*bx + by*by) + bz*bz);       \
        float lc = __builtin_amdgcn_sqrtf((cx*cx + cy*cy) + cz*cz);       \
        float ux = by*cz - bz*cy;                                         \
        float uy = bz*cx - bx*cz;                                         \
        float uz = bx*cy - by*cx;                                         \
        float det = (ax*ux + ay*uy) + az*uz;                              \
        float dab = (ax*bx + ay*by) + az*bz;                              \
        float dbc = (bx*cx + by*cy) + bz*cz;                              \
        float dca = (cx*ax + cy*ay) + cz*az;                              \
        float denom = la*lb*lc + dab*lc + dbc*la + dca*lb;                \
        S += fast_atan2f(det, denom);                                     \
    }

// Fat kernel: blocks [0, WN_BLOCKS) = winding numbers (VALU-heavy, critical
// path, launched first); [WN_BLOCKS, WN_BLOCKS+V2V_BLOCKS) = masked min
// distance (memory-heavy, hides under wn VALU saturation).
__global__ __launch_bounds__(256) void fused_kernel(
    const float4* __restrict__ tris12, const float4* __restrict__ x4,
    float* __restrict__ partials,
    const void* __restrict__ gm, const int* __restrict__ flag_p,
    float* __restrict__ out)
{
    if (blockIdx.x < WN_BLOCKS) {
        // ------- winding numbers: 4 points/thread, ping-pong prefetch -------
        int tc = blockIdx.x / PBLK;           // consecutive blocks share chunk
        int pb = blockIdx.x - tc * PBLK;
        int pt = pb * 256 + threadIdx.x;
        if (pt >= QTR) return;                // no barriers below -> safe exit

        float4 P0 = x4[pt];
        float4 P1 = x4[pt + QTR];
        float4 P2 = x4[pt + 2*QTR];
        float4 P3 = x4[pt + 3*QTR];

        const float4* __restrict__ T = tris12 + (size_t)tc * (TPC * 3);

        float4 A0 = T[0], B0 = T[1], C0 = T[2];
        float4 A1 = T[3], B1 = T[4], C1 = T[5];
        double acc0 = 0.0, acc1 = 0.0, acc2 = 0.0, acc3 = 0.0;

        for (int kk = 0; kk < TPC; kk += 2) {
            int n0 = 3 * min(kk + 2, TPC - 1);   // guarded prefetch (in-bounds)
            int n1 = 3 * min(kk + 3, TPC - 1);
            float s0 = 0.f, s1 = 0.f, s2 = 0.f, s3 = 0.f;

            TRI_OMEGA(A0, B0, C0, P0.x, P0.y, P0.z, s0);
            TRI_OMEGA(A0, B0, C0, P1.x, P1.y, P1.z, s1);
            TRI_OMEGA(A0, B0, C0, P2.x, P2.y, P2.z, s2);
            TRI_OMEGA(A0, B0, C0, P3.x, P3.y, P3.z, s3);
            A0 = T[n0]; B0 = T[n0 + 1]; C0 = T[n0 + 2];

            TRI_OMEGA(A1, B1, C1, P0.x, P0.y, P0.z, s0);
            TRI_OMEGA(A1, B1, C1, P1.x, P1.y, P1.z, s1);
            TRI_OMEGA(A1, B1, C1, P2.x, P2.y, P2.z, s2);
            TRI_OMEGA(A1, B1, C1, P3.x, P3.y, P3.z, s3);
            A1 = T[n1]; B1 = T[n1 + 1]; C1 = T[n1 + 2];

            acc0 += (double)s0;
            acc1 += (double)s1;
            acc2 += (double)s2;
            acc3 += (double)s3;
        }

        float* prow = partials + (size_t)tc * NVPAD;
        prow[pt]         = (float)acc0;
        prow[pt +   QTR] = (float)acc1;
        prow[pt + 2*QTR] = (float)acc2;
        prow[pt + 3*QTR] = (float)acc3;
    } else {
        // ---------- v2v: one wave per row j, lane-stride-1 over i ----------
        int bid = blockIdx.x - WN_BLOCKS;
        int w = threadIdx.x >> 6;
        int lane = threadIdx.x & 63;
        int j = bid * 4 + w;
        if (j >= NV) return;

        int flag = *flag_p;
        float4 vj = x4[j];
        float m = INFINITY;

#define V2V_BODY(GTEST)                                            \
        {                                                          \
            int i0 = 0;                                            \
            _Pragma("unroll 4")                                    \
            for (; i0 + 64 <= NV; i0 += 64) {                      \
                int i = i0 + lane;                                 \
                bool g = (GTEST);                                  \
                float4 vi = x4[i];                                 \
                float dot = (vi.x*vj.x + vi.y*vj.y) + vi.z*vj.z;   \
                float d2  = vi.w + vj.w - 2.0f*dot;                \
                m = fminf(m, g ? d2 : INFINITY);                   \
            }                                                      \
            int i = i0 + lane;                                     \
            if (i < NV) {                                          \
                bool g = (GTEST);                                  \
                float4 vi = x4[i];                                 \
                float dot = (vi.x*vj.x + vi.y*vj.y) + vi.z*vj.z;   \
                float d2  = vi.w + vj.w - 2.0f*dot;                \
                m = fminf(m, g ? d2 : INFINITY);                   \
            }                                                      \
        }

        if (flag == 0) {
            const unsigned char* row = (const unsigned char*)gm + (size_t)j * NV;
            V2V_BODY(row[i] != 0)
        } else if (flag == 1) {
            const int* row = (const int*)gm + (size_t)j * NV;
            V2V_BODY(row[i] != 0)
        } else {
            const float* row = (const float*)gm + (size_t)j * NV;
            V2V_BODY(row[i] != 0.0f)
        }
#undef V2V_BODY

        #pragma unroll
        for (int k = 32; k > 0; k >>= 1)
            m = fminf(m, __shfl_xor(m, k, 64));
        if (lane == 0) {
            float d = __builtin_amdgcn_sqrtf(fmaxf(m, 0.f));
            out[j] = d;                                   // v2v_min
            out[NV + j] = (d < EUCL_THRES) ? 1.f : 0.f;   // incontact
        }
    }
}

__global__ __launch_bounds__(256) void wn_reduce_kernel(
    const float* __restrict__ partials, float* __restrict__ out_exterior)
{
    int pt = blockIdx.x * 256 + threadIdx.x;
    if (pt >= NV) return;
    double s = 0.0;
    for (int t = 0; t < TCH; ++t) s += (double)partials[(size_t)t * NVPAD + pt];
    double wn = (2.0 * s) / 12.566370614359172953850573533118;  // (2*sum)/(4*pi)
    out_exterior[pt] = (wn <= WN_THRES) ? 1.0f : 0.0f;
}

extern "C" void kernel_launch(void* const* d_in, const int* in_sizes, int n_in,
                              void* d_out, int out_size, void* d_ws, size_t ws_size,
                              hipStream_t stream)
{
    const float* verts = (const float*)d_in[0];
    const int*   faces = (const int*)d_in[1];
    const void*  gm    = d_in[2];
    float* out = (float*)d_out;
    char* ws = (char*)d_ws;

    int*   flag     = (int*)ws;
    float* tris12   = (float*)(ws + WS_TRIS_OFF);
    float* x4       = (float*)(ws + WS_X4_OFF);
    float* partials = (float*)(ws + WS_PART_OFF);

    prep_kernel<<<NFPAD / 256, 256, 0, stream>>>(
        verts, faces, (const unsigned char*)gm, tris12, x4, flag);

    fused_kernel<<<WN_BLOCKS + V2V_BLOCKS, 256, 0, stream>>>(
        (const float4*)tris12, (const float4*)x4, partials, gm, flag, out);

    wn_reduce_kernel<<<RED_BLOCKS, 256, 0, stream>>>(partials, out + 2 * NV);
}

// Round 8
// 454.077 us; speedup vs baseline: 1.0179x; 1.0179x over previous
//
#include <hip/hip_runtime.h>
#include <math.h>

#define NV 6890
#define NF 13776
#define NVPAD 6912            // 27 * 256
#define NFPAD 13824
#define HALF 3456             // NVPAD/2
#define V2V_BLOCKS 1723       // ceil(NV/4)
#define RED_BLOCKS 27
#define WN_THRES 0.99
#define EUCL_THRES 0.02f

// fallback (round-5) geometry
#define TCH_FB 64
#define TPC_FB 216
#define PBLK_FB 14
#define WNB_FB (TCH_FB*PBLK_FB)    // 896
// table-path geometry
#define TCH_TB 128
#define TPC_TB 108
#define PBLK_TB 14
#define WNB_TB (TCH_TB*PBLK_TB)    // 1792

// ws layout (bytes):
//  [0,4)        flag; [64, +NFPAD*48) tri records (either rep);
//  x4; partials (TCH_TB rows, fallback uses first 64); table (gated).
#define WS_TRIS_OFF   64
#define WS_X4_OFF     (64 + NFPAD*48)             // 663616
#define WS_PART_OFF   (WS_X4_OFF + NVPAD*16)      // 774208
#define WS_TAB_OFF    (((WS_PART_OFF + TCH_TB*NVPAD*4) + 255) & ~(size_t)255) // 4313344
#define WS_TAB_BYTES  ((size_t)NV * NVPAD * 4)    // 190,494,720

// mode 0: tris12 raw coords (fallback). mode 1: {n,d0,eab,ebc,eca,ids} records.
__global__ __launch_bounds__(256) void prep_kernel(
    const float* __restrict__ verts, const int* __restrict__ faces,
    const unsigned char* __restrict__ gm_bytes,
    float* __restrict__ tris, float* __restrict__ x4, int* __restrict__ flag,
    int mode)
{
    int t = blockIdx.x * 256 + threadIdx.x;

    if (t < NFPAD) {
        float* o = tris + (size_t)t * 12;
        if (t < NF) {
            int ia = faces[t*3+0], ib = faces[t*3+1], ic = faces[t*3+2];
            float Ax = verts[ia*3+0], Ay = verts[ia*3+1], Az = verts[ia*3+2];
            float Bx = verts[ib*3+0], By = verts[ib*3+1], Bz = verts[ib*3+2];
            float Cx = verts[ic*3+0], Cy = verts[ic*3+1], Cz = verts[ic*3+2];
            if (mode == 0) {
                o[0]=Ax; o[1]=Ay; o[2]=Az;  o[3]=0.f;
                o[4]=Bx; o[5]=By; o[6]=Bz;  o[7]=0.f;
                o[8]=Cx; o[9]=Cy; o[10]=Cz; o[11]=0.f;
            } else {
                float e1x=Bx-Ax, e1y=By-Ay, e1z=Bz-Az;
                float e2x=Cx-Ax, e2y=Cy-Ay, e2z=Cz-Az;
                float nx = e1y*e2z - e1z*e2y;
                float ny = e1z*e2x - e1x*e2z;
                float nz = e1x*e2y - e1y*e2x;
                float d0 = (nx*Ax + ny*Ay) + nz*Az;
                float eab = (e1x*e1x + e1y*e1y) + e1z*e1z;            // |A-B|^2
                float bcx=Cx-Bx, bcy=Cy-By, bcz=Cz-Bz;
                float ebc = (bcx*bcx + bcy*bcy) + bcz*bcz;            // |B-C|^2
                float eca = (e2x*e2x + e2y*e2y) + e2z*e2z;            // |C-A|^2
                o[0]=nx; o[1]=ny; o[2]=nz; o[3]=d0;
                o[4]=eab; o[5]=ebc; o[6]=eca; o[7]=0.f;
                o[8]=__int_as_float(ia); o[9]=__int_as_float(ib);
                o[10]=__int_as_float(ic); o[11]=0.f;
            }
        } else {
            #pragma unroll
            for (int q = 0; q < 12; ++q) o[q] = 0.f;   // pad tri -> omega 0
        }
    }
    if (t < NVPAD) {
        if (t < NV) {
            float x = verts[t*3+0], y = verts[t*3+1], z = verts[t*3+2];
            x4[t*4+0] = x; x4[t*4+1] = y; x4[t*4+2] = z;
            x4[t*4+3] = (x*x + y*y) + z*z;
        } else {
            x4[t*4+0] = 0.f; x4[t*4+1] = 0.f; x4[t*4+2] = 0.f; x4[t*4+3] = 0.f;
        }
    }
    if (blockIdx.x == 0 && threadIdx.x < 64) {
        int lane = threadIdx.x;
        bool any3F = false, anyNZmod = false;
        for (int k = 0; k < 64; ++k) {
            int off = lane * 64 + k;
            unsigned char b = gm_bytes[off];
            if ((off & 3) == 3 && (b == 0x3F || b == 0xBF)) any3F = true;
            if ((off & 3) != 0 && b != 0) anyNZmod = true;
        }
        unsigned long long m3F = __ballot(any3F);
        unsigned long long mNZ = __ballot(anyNZmod);
        if (lane == 0) *flag = m3F ? 2 : (mNZ ? 0 : 1);
    }
}

// D[v][p] = |x_v - x_p|, p padded to NVPAD (pad cols vs origin, ignored later)
__global__ __launch_bounds__(256) void tab_kernel(
    const float4* __restrict__ x4, float* __restrict__ D)
{
    int p = blockIdx.x * 256 + threadIdx.x;   // [0, NVPAD)
    int v = blockIdx.y;                       // [0, NV)
    float4 Pv = x4[v];                        // uniform -> scalar
    float4 Pp = x4[p];
    float dx = Pv.x - Pp.x, dy = Pv.y - Pp.y, dz = Pv.z - Pp.z;
    D[(size_t)v * NVPAD + p] = __builtin_amdgcn_sqrtf((dx*dx + dy*dy) + dz*dz);
}

__device__ __forceinline__ float fast_atan2f(float y, float x)
{
    float ay = __builtin_fabsf(y), ax = __builtin_fabsf(x);
    float mx = fmaxf(ax, ay);
    float mn = fminf(ax, ay);
    float r  = __builtin_amdgcn_rcpf(fmaxf(mx, 1e-37f));
    float t  = mn * r;
    float s  = t * t;
    float u  =              0.00282363896258175373077393f;
    u = fmaf(u, s, -0.0159569028764963150024414f);
    u = fmaf(u, s,  0.0425049886107444763183594f);
    u = fmaf(u, s, -0.0748900920152664184570312f);
    u = fmaf(u, s,  0.106347933411598205566406f);
    u = fmaf(u, s, -0.142027363181114196777344f);
    u = fmaf(u, s,  0.199926957488059997558594f);
    u = fmaf(u, s, -0.333331018686294555664062f);
    float p = fmaf(s * u, t, t);
    p = (ay > ax)  ? (1.5707963267948966f - p) : p;
    p = (x < 0.0f) ? (3.14159265358979323846f - p) : p;
    return copysignf(p, y);
}

// ============================= TABLE PATH =============================
// per (point,tri): dists from table; dots via law of cosines; det = d0 - n.p
#define OMEGA_TAB(LA, LB, LC, PX, PY, PZ, S)                               \
    {                                                                      \
        float la2 = LA*LA, lb2 = LB*LB, lc2 = LC*LC;                       \
        float dab = (la2 + lb2 - eab) * 0.5f;                              \
        float dbc = (lb2 + lc2 - ebc) * 0.5f;                              \
        float dca = (lc2 + la2 - eca) * 0.5f;                              \
        float det = d0 - ((nx*PX + ny*PY) + nz*PZ);                        \
        float t3  = (LA*LB)*LC;                                            \
        float denom = fmaf(dca, LB, fmaf(dbc, LA, fmaf(dab, LC, t3)));     \
        float o = fast_atan2f(det, denom);                                 \
        S += (t3 != 0.0f) ? o : 0.0f;  /* p==vertex must give exactly 0 */ \
    }

__global__ __launch_bounds__(256) void fused_tab_kernel(
    const float* __restrict__ consts, const float* __restrict__ Dt,
    const float4* __restrict__ x4, float* __restrict__ partials,
    const void* __restrict__ gm, const int* __restrict__ flag_p,
    float* __restrict__ out)
{
    if (blockIdx.x < WNB_TB) {
        int tc = blockIdx.x / PBLK_TB;
        int pb = blockIdx.x - tc * PBLK_TB;
        int pt = pb * 256 + threadIdx.x;
        if (pt >= HALF) return;
        int ptH = pt + HALF;

        float4 P0 = x4[pt];
        float4 P1 = x4[ptH];

        const float* cvb = consts + (size_t)tc * TPC_TB * 12;
        double acc0 = 0.0, acc1 = 0.0;

        for (int k = 0; k < TPC_TB; k += 2) {
            float s0 = 0.f, s1 = 0.f;
            #pragma unroll
            for (int u = 0; u < 2; ++u) {
                const float* cv = cvb + (size_t)(k + u) * 12;
                float nx = cv[0], ny = cv[1], nz = cv[2], d0 = cv[3];
                float eab = cv[4], ebc = cv[5], eca = cv[6];
                int ia = __float_as_int(cv[8]);
                int ib = __float_as_int(cv[9]);
                int ic = __float_as_int(cv[10]);
                const float* rA = Dt + (size_t)ia * NVPAD;   // uniform rows
                const float* rB = Dt + (size_t)ib * NVPAD;
                const float* rC = Dt + (size_t)ic * NVPAD;
                float la0 = rA[pt],  lb0 = rB[pt],  lc0 = rC[pt];
                float la1 = rA[ptH], lb1 = rB[ptH], lc1 = rC[ptH];
                OMEGA_TAB(la0, lb0, lc0, P0.x, P0.y, P0.z, s0);
                OMEGA_TAB(la1, lb1, lc1, P1.x, P1.y, P1.z, s1);
            }
            acc0 += (double)s0;
            acc1 += (double)s1;
        }

        float* prow = partials + (size_t)tc * NVPAD;
        prow[pt]  = (float)acc0;
        prow[ptH] = (float)acc1;
    } else {
        // v2v from table: one wave per row, min of masked D[j][i]
        int bid = blockIdx.x - WNB_TB;
        int w = threadIdx.x >> 6;
        int lane = threadIdx.x & 63;
        int j = bid * 4 + w;
        if (j >= NV) return;

        int flag = *flag_p;
        const float* Dr = Dt + (size_t)j * NVPAD;
        float m = INFINITY;

#define V2V_TAB(GTEST)                                             \
        {                                                          \
            int i0 = 0;                                            \
            _Pragma("unroll 4")                                    \
            for (; i0 + 64 <= NV; i0 += 64) {                      \
                int i = i0 + lane;                                 \
                bool g = (GTEST);                                  \
                float d = Dr[i];                                   \
                m = fminf(m, g ? d : INFINITY);                    \
            }                                                      \
            int i = i0 + lane;                                     \
            if (i < NV) {                                          \
                bool g = (GTEST);                                  \
                float d = Dr[i];                                   \
                m = fminf(m, g ? d : INFINITY);                    \
            }                                                      \
        }
        if (flag == 0) {
            const unsigned char* row = (const unsigned char*)gm + (size_t)j * NV;
            V2V_TAB(row[i] != 0)
        } else if (flag == 1) {
            const int* row = (const int*)gm + (size_t)j * NV;
            V2V_TAB(row[i] != 0)
        } else {
            const float* row = (const float*)gm + (size_t)j * NV;
            V2V_TAB(row[i] != 0.0f)
        }
#undef V2V_TAB

        #pragma unroll
        for (int k = 32; k > 0; k >>= 1)
            m = fminf(m, __shfl_xor(m, k, 64));
        if (lane == 0) {
            out[j] = m;
            out[NV + j] = (m < EUCL_THRES) ? 1.f : 0.f;
        }
    }
}

__global__ __launch_bounds__(256) void reduce_tab_kernel(
    const float* __restrict__ partials, float* __restrict__ out_exterior)
{
    int pt = blockIdx.x * 256 + threadIdx.x;
    if (pt >= NV) return;
    double s = 0.0;
    for (int t = 0; t < TCH_TB; ++t) s += (double)partials[(size_t)t * NVPAD + pt];
    double wn = (2.0 * s) / 12.566370614359172953850573533118;
    out_exterior[pt] = (wn <= WN_THRES) ? 1.0f : 0.0f;
}

// ============================ FALLBACK (round-5, proven) ============================
#define TRI_OMEGA(A, B, C, PX, PY, PZ, S)                                 \
    {                                                                     \
        float ax = A.x - PX, ay = A.y - PY, az = A.z - PZ;                \
        float bx = B.x - PX, by = B.y - PY, bz = B.z - PZ;                \
        float cx = C.x - PX, cy = C.y - PY, cz = C.z - PZ;                \
        float la = __builtin_amdgcn_sqrtf((ax*ax + ay*ay) + az*az);       \
        float lb = __builtin_amdgcn_sqrtf((bx*bx + by*by) + bz*bz);       \
        float lc = __builtin_amdgcn_sqrtf((cx*cx + cy*cy) + cz*cz);       \
        float ux = by*cz - bz*cy;                                         \
        float uy = bz*cx - bx*cz;                                         \
        float uz = bx*cy - by*cx;                                         \
        float det = (ax*ux + ay*uy) + az*uz;                              \
        float dab = (ax*bx + ay*by) + az*bz;                              \
        float dbc = (bx*cx + by*cy) + bz*cz;                              \
        float dca = (cx*ax + cy*ay) + cz*az;                              \
        float denom = la*lb*lc + dab*lc + dbc*la + dca*lb;                \
        S += fast_atan2f(det, denom);                                     \
    }

__global__ __launch_bounds__(256) void fused_fb_kernel(
    const float4* __restrict__ tris12, const float4* __restrict__ x4,
    float* __restrict__ partials,
    const void* __restrict__ gm, const int* __restrict__ flag_p,
    float* __restrict__ out)
{
    if (blockIdx.x < WNB_FB) {
        int tc = blockIdx.x / PBLK_FB;
        int pb = blockIdx.x - tc * PBLK_FB;
        int pt = pb * 256 + threadIdx.x;
        if (pt >= HALF) return;
        int p1i = pt + HALF;

        float4 P0 = x4[pt];
        float4 P1 = x4[p1i];
        float px0 = P0.x, py0 = P0.y, pz0 = P0.z;
        float px1 = P1.x, py1 = P1.y, pz1 = P1.z;

        const float4* __restrict__ T = tris12 + (size_t)tc * (TPC_FB * 3);

        float4 A0 = T[0], B0 = T[1], C0 = T[2];
        float4 A1 = T[3], B1 = T[4], C1 = T[5];
        double acc0 = 0.0, acc1 = 0.0;

        for (int kk = 0; kk < TPC_FB; kk += 2) {
            int n0 = 3 * min(kk + 2, TPC_FB - 1);
            int n1 = 3 * min(kk + 3, TPC_FB - 1);
            float s0 = 0.f, s1 = 0.f;

            TRI_OMEGA(A0, B0, C0, px0, py0, pz0, s0);
            TRI_OMEGA(A0, B0, C0, px1, py1, pz1, s1);
            A0 = T[n0]; B0 = T[n0 + 1]; C0 = T[n0 + 2];

            TRI_OMEGA(A1, B1, C1, px0, py0, pz0, s0);
            TRI_OMEGA(A1, B1, C1, px1, py1, pz1, s1);
            A1 = T[n1]; B1 = T[n1 + 1]; C1 = T[n1 + 2];

            acc0 += (double)s0;
            acc1 += (double)s1;
        }

        partials[(size_t)tc * NVPAD + pt]  = (float)acc0;
        partials[(size_t)tc * NVPAD + p1i] = (float)acc1;
    } else {
        int bid = blockIdx.x - WNB_FB;
        int w = threadIdx.x >> 6;
        int lane = threadIdx.x & 63;
        int j = bid * 4 + w;
        if (j >= NV) return;

        int flag = *flag_p;
        float4 vj = x4[j];
        float m = INFINITY;

#define V2V_BODY(GTEST)                                            \
        {                                                          \
            int i0 = 0;                                            \
            _Pragma("unroll 4")                                    \
            for (; i0 + 64 <= NV; i0 += 64) {                      \
                int i = i0 + lane;                                 \
                bool g = (GTEST);                                  \
                float4 vi = x4[i];                                 \
                float dot = (vi.x*vj.x + vi.y*vj.y) + vi.z*vj.z;   \
                float d2  = vi.w + vj.w - 2.0f*dot;                \
                m = fminf(m, g ? d2 : INFINITY);                   \
            }                                                      \
            int i = i0 + lane;                                     \
            if (i < NV) {                                          \
                bool g = (GTEST);                                  \
                float4 vi = x4[i];                                 \
                float dot = (vi.x*vj.x + vi.y*vj.y) + vi.z*vj.z;   \
                float d2  = vi.w + vj.w - 2.0f*dot;                \
                m = fminf(m, g ? d2 : INFINITY);                   \
            }                                                      \
        }
        if (flag == 0) {
            const unsigned char* row = (const unsigned char*)gm + (size_t)j * NV;
            V2V_BODY(row[i] != 0)
        } else if (flag == 1) {
            const int* row = (const int*)gm + (size_t)j * NV;
            V2V_BODY(row[i] != 0)
        } else {
            const float* row = (const float*)gm + (size_t)j * NV;
            V2V_BODY(row[i] != 0.0f)
        }
#undef V2V_BODY

        #pragma unroll
        for (int k = 32; k > 0; k >>= 1)
            m = fminf(m, __shfl_xor(m, k, 64));
        if (lane == 0) {
            float d = __builtin_amdgcn_sqrtf(fmaxf(m, 0.f));
            out[j] = d;
            out[NV + j] = (d < EUCL_THRES) ? 1.f : 0.f;
        }
    }
}

__global__ __launch_bounds__(256) void reduce_fb_kernel(
    const float* __restrict__ partials, float* __restrict__ out_exterior)
{
    int pt = blockIdx.x * 256 + threadIdx.x;
    if (pt >= NV) return;
    double s = 0.0;
    for (int t = 0; t < TCH_FB; ++t) s += (double)partials[(size_t)t * NVPAD + pt];
    double wn = (2.0 * s) / 12.566370614359172953850573533118;
    out_exterior[pt] = (wn <= WN_THRES) ? 1.0f : 0.0f;
}

extern "C" void kernel_launch(void* const* d_in, const int* in_sizes, int n_in,
                              void* d_out, int out_size, void* d_ws, size_t ws_size,
                              hipStream_t stream)
{
    const float* verts = (const float*)d_in[0];
    const int*   faces = (const int*)d_in[1];
    const void*  gm    = d_in[2];
    float* out = (float*)d_out;
    char* ws = (char*)d_ws;

    int*   flag     = (int*)ws;
    float* tris     = (float*)(ws + WS_TRIS_OFF);
    float* x4       = (float*)(ws + WS_X4_OFF);
    float* partials = (float*)(ws + WS_PART_OFF);
    float* Dt       = (float*)(ws + WS_TAB_OFF);

    size_t need = (size_t)WS_TAB_OFF + WS_TAB_BYTES;
    if (ws_size >= need) {
        prep_kernel<<<NFPAD / 256, 256, 0, stream>>>(
            verts, faces, (const unsigned char*)gm, tris, x4, flag, 1);
        tab_kernel<<<dim3(NVPAD / 256, NV), 256, 0, stream>>>(
            (const float4*)x4, Dt);
        fused_tab_kernel<<<WNB_TB + V2V_BLOCKS, 256, 0, stream>>>(
            tris, Dt, (const float4*)x4, partials, gm, flag, out);
        reduce_tab_kernel<<<RED_BLOCKS, 256, 0, stream>>>(partials, out + 2 * NV);
    } else {
        prep_kernel<<<NFPAD / 256, 256, 0, stream>>>(
            verts, faces, (const unsigned char*)gm, tris, x4, flag, 0);
        fused_fb_kernel<<<WNB_FB + V2V_BLOCKS, 256, 0, stream>>>(
            (const float4*)tris, (const float4*)x4, partials, gm, flag, out);
        reduce_fb_kernel<<<RED_BLOCKS, 256, 0, stream>>>(partials, out + 2 * NV);
    }
}